// Round 1
// baseline (132.301 us; speedup 1.0000x reference)
//
#include <hip/hip_runtime.h>
#include <math.h>

#define D_ 96
#define L_ 4096
#define K_ 8
#define N_ 16
#define R_ 6
#define CDBL 38   // R + 2N
#define DL_ (D_ * L_)

__device__ __forceinline__ float softplusf(float x) {
    return (x > 20.f) ? x : log1pf(expf(x));
}

// K1: cross_scan — xs[k][d][l] from x[d][h][w]
__global__ void k_cross_scan(const float* __restrict__ x, float* __restrict__ xs) {
    int idx = blockIdx.x * blockDim.x + threadIdx.x; // d*L + l
    if (idx >= DL_) return;
    int l = idx & 4095;
    int d = idx >> 12;
    const float* xd = x + d * L_;
    int h1 = l & 63, w1 = l >> 6;        // l = w1*H + h1 (for transposed views)
    int lp = 4095 - l;
    int h3 = lp & 63, w3 = lp >> 6;
    xs[0 * DL_ + idx] = xd[l];
    xs[2 * DL_ + idx] = xd[4095 - l];
    xs[1 * DL_ + idx] = xd[h1 * 64 + w1];
    xs[3 * DL_ + idx] = xd[h3 * 64 + w3];
    xs[4 * DL_ + idx] = xd[h1 * 64 + ((h1 + w1) & 63)];
    xs[5 * DL_ + idx] = xd[h1 * 64 + ((w1 - h1) & 63)];
    xs[6 * DL_ + idx] = xd[h3 * 64 + ((h3 + w3) & 63)];
    xs[7 * DL_ + idx] = xd[h3 * 64 + ((w3 - h3) & 63)];
}

// K2: x_dbl[k][c][l] = sum_d wproj[k][c][d] * xs[k][d][l]   (LDS-tiled over 128 l)
__global__ __launch_bounds__(256) void k_xdbl(const float* __restrict__ xs,
                                              const float* __restrict__ wproj,
                                              float* __restrict__ xdbl) {
    __shared__ float tile[D_ * 128];
    int k = blockIdx.x >> 5;
    int l0 = (blockIdx.x & 31) * 128;
    const float* src = xs + k * DL_;
    for (int e = threadIdx.x; e < D_ * 128; e += 256) {
        int d = e >> 7, li = e & 127;
        tile[e] = src[d * L_ + l0 + li];
    }
    __syncthreads();
    int lt = threadIdx.x & 127;
    int c0 = threadIdx.x >> 7;  // 0 or 1
    const float* wk = wproj + k * CDBL * D_;
    for (int c = c0; c < CDBL; c += 2) {
        float acc = 0.f;
        const float* wc = wk + c * D_;
        #pragma unroll 8
        for (int d = 0; d < D_; ++d)
            acc = fmaf(wc[d], tile[d * 128 + lt], acc);
        xdbl[k * CDBL * L_ + c * L_ + l0 + lt] = acc;
    }
}

// K3: delta[k][d][l] = softplus( sum_r dtw[k][d][r]*xdbl[k][r][l] + dtb[k][d] )
__global__ void k_delta(const float* __restrict__ xdbl,
                        const float* __restrict__ dtw,
                        const float* __restrict__ dtb,
                        float* __restrict__ delta) {
    int idx = blockIdx.x * blockDim.x + threadIdx.x; // (k*96+d)*L + l
    if (idx >= K_ * DL_) return;
    int l = idx & 4095;
    int kd = idx >> 12;
    int k = kd / D_;
    const float* xr = xdbl + k * CDBL * L_;
    const float* w = dtw + kd * R_;
    float s = dtb[kd];
    #pragma unroll
    for (int r = 0; r < R_; ++r)
        s = fmaf(w[r], xr[r * L_ + l], s);
    delta[idx] = softplusf(s);
}

// K4: selective scan. One block per (k,d) chain. Thread t owns l in [16t,16t+16).
// Parallel scan: register-local scan (16) -> Kogge-Stone over 64 lanes -> LDS for
// 4 wave aggregates. u (=xs) is preloaded so y can overwrite it in place.
__global__ __launch_bounds__(256) void k_scan(const float* __restrict__ delta,
                                              const float* __restrict__ xdbl,
                                              const float* __restrict__ alogs,
                                              const float* __restrict__ dsv_,
                                              float* __restrict__ u_ys) {
    int kd = blockIdx.x;
    int k = kd / D_;
    int t = threadIdx.x;
    int lane = t & 63, wv = t >> 6;
    const float* dptr = delta + kd * L_ + t * 16;
    float* uptr = u_ys + kd * L_ + t * 16;
    float d16[16], u16[16], y16[16];
    #pragma unroll
    for (int i = 0; i < 16; i += 4) {
        *(float4*)(d16 + i) = *(const float4*)(dptr + i);
        *(float4*)(u16 + i) = *(const float4*)(uptr + i);
        y16[i] = y16[i + 1] = y16[i + 2] = y16[i + 3] = 0.f;
    }
    const float* Bbase = xdbl + k * CDBL * L_ + R_ * L_ + t * 16;
    const float* Cbase = Bbase + N_ * L_;
    const float* arow = alogs + kd * N_;
    __shared__ float lds_a[4], lds_b[4];
    for (int n = 0; n < N_; ++n) {
        float An = -expf(arow[n]);
        const float* Bp = Bbase + n * L_;
        float aa[16], bb[16];
        float ra = 1.f, rb = 0.f;
        #pragma unroll
        for (int i = 0; i < 16; ++i) {
            float a = expf(d16[i] * An);
            float b = d16[i] * Bp[i] * u16[i];
            rb = fmaf(a, rb, b);
            ra = a * ra;
            aa[i] = ra; bb[i] = rb;
        }
        // inclusive Kogge-Stone scan of (ra,rb) across 64 lanes
        float sa = ra, sb = rb;
        #pragma unroll
        for (int off = 1; off < 64; off <<= 1) {
            float pa = __shfl_up(sa, off);
            float pb = __shfl_up(sb, off);
            if (lane >= off) { sb = fmaf(sa, pb, sb); sa *= pa; }
        }
        // exclusive within-wave prefix
        float ea = __shfl_up(sa, 1);
        float eb = __shfl_up(sb, 1);
        if (lane == 0) { ea = 1.f; eb = 0.f; }
        if (lane == 63) { lds_a[wv] = sa; lds_b[wv] = sb; }
        __syncthreads();
        float cb = 0.f;
        for (int w2 = 0; w2 < wv; ++w2) {
            cb = fmaf(lds_a[w2], cb, lds_b[w2]);
        }
        __syncthreads();
        float hprev = fmaf(ea, cb, eb);   // state entering this thread's segment
        const float* Cp = Cbase + n * L_;
        #pragma unroll
        for (int i = 0; i < 16; ++i) {
            float h = fmaf(aa[i], hprev, bb[i]);
            y16[i] = fmaf(Cp[i], h, y16[i]);
        }
    }
    float dval = dsv_[kd];
    #pragma unroll
    for (int i = 0; i < 16; ++i) y16[i] = fmaf(dval, u16[i], y16[i]);
    #pragma unroll
    for (int i = 0; i < 16; i += 4)
        *(float4*)(uptr + i) = *(float4*)(y16 + i);
}

// K5a: cross_merge — wsy[d][l] = sum of 8 inverse-permuted ys slices
__global__ void k_merge(const float* __restrict__ ys, float* __restrict__ wsy) {
    int idx = blockIdx.x * blockDim.x + threadIdx.x; // d*L + l
    if (idx >= DL_) return;
    int l = idx & 4095;
    int d = idx >> 12;
    int h = l >> 6, w = l & 63;
    int i1 = (w << 6) + h;
    int i4 = (((w - h) & 63) << 6) + h;
    int i5 = (((w + h) & 63) << 6) + h;
    const float* bd = ys + d * L_;
    float v = bd[0 * DL_ + l]
            + bd[2 * DL_ + 4095 - l]
            + bd[1 * DL_ + i1]
            + bd[3 * DL_ + 4095 - i1]
            + bd[4 * DL_ + i4]
            + bd[6 * DL_ + 4095 - i4]
            + bd[5 * DL_ + i5]
            + bd[7 * DL_ + 4095 - i5];
    wsy[idx] = v;
}

// K5b: LayerNorm over channels per position, write [H,W,D]
__global__ void k_ln(const float* __restrict__ wsy, const float* __restrict__ gamma,
                     const float* __restrict__ beta, float* __restrict__ out) {
    int l = blockIdx.x * blockDim.x + threadIdx.x;
    if (l >= L_) return;
    float sum = 0.f, sq = 0.f;
    for (int d = 0; d < D_; ++d) {
        float v = wsy[d * L_ + l];
        sum += v; sq = fmaf(v, v, sq);
    }
    float mu = sum * (1.f / 96.f);
    float var = sq * (1.f / 96.f) - mu * mu;
    float rs = rsqrtf(var + 1e-5f);
    float* op = out + l * D_;
    for (int d = 0; d < D_; ++d) {
        float v = wsy[d * L_ + l];
        op[d] = fmaf((v - mu) * rs, gamma[d], beta[d]);
    }
}

extern "C" void kernel_launch(void* const* d_in, const int* in_sizes, int n_in,
                              void* d_out, int out_size, void* d_ws, size_t ws_size,
                              hipStream_t stream) {
    const float* x     = (const float*)d_in[0];
    const float* wproj = (const float*)d_in[1];
    const float* dtw   = (const float*)d_in[2];
    const float* dtb   = (const float*)d_in[3];
    const float* alogs = (const float*)d_in[4];
    const float* dsv   = (const float*)d_in[5];
    const float* gamma = (const float*)d_in[6];
    const float* beta  = (const float*)d_in[7];
    float* out = (float*)d_out;
    float* ws  = (float*)d_ws;

    float* xs    = ws;                       // K*D*L = 3145728 floats (also ys)
    float* xdbl  = ws + 3145728;             // K*38*L = 1245184 floats
    float* delta = ws + 4390912;             // K*D*L floats (also merge buffer)

    hipLaunchKernelGGL(k_cross_scan, dim3(DL_ / 256), dim3(256), 0, stream, x, xs);
    hipLaunchKernelGGL(k_xdbl, dim3(K_ * 32), dim3(256), 0, stream, xs, wproj, xdbl);
    hipLaunchKernelGGL(k_delta, dim3(K_ * DL_ / 256), dim3(256), 0, stream,
                       xdbl, dtw, dtb, delta);
    hipLaunchKernelGGL(k_scan, dim3(K_ * D_), dim3(256), 0, stream,
                       delta, xdbl, alogs, dsv, xs);
    hipLaunchKernelGGL(k_merge, dim3(DL_ / 256), dim3(256), 0, stream, xs, delta);
    hipLaunchKernelGGL(k_ln, dim3(L_ / 256), dim3(256), 0, stream,
                       delta, gamma, beta, out);
}